// Round 1
// baseline (6384.196 us; speedup 1.0000x reference)
//
#include <hip/hip_runtime.h>
#include <math.h>

// Problem constants (B=256, T=784, H=512, C=10)
#define TSTEPS 784
#define BATCH  256
#define HID    512
#define NCLS   10

// Decomposition: 32 groups x 8 member-blocks. Each member holds a 64-column
// slice of W in LDS (512*64*4 = 128 KB); each group owns 8 batch rows.
// Per step each block computes h_new[8 x 64cols] and groups exchange h via a
// double-buffered global buffer + an 8-party atomic barrier (agent scope).
#define NBLK   256
#define NGRP   32
#define MEMB   8
#define BPG    8     // batch rows per group
#define JS     64    // output columns per block
#define NTHR   512

#define SMEM_FLOATS (HID*JS + BPG*HID)   // W slice + h stage/partials = 36864 f32 = 144 KB
#define CNT_STRIDE  32                   // pad barrier counters to 128 B (no false sharing)

__device__ __forceinline__ float fast_tanh(float x) {
    // tanh(x) = sign(x) * (1 - 2/(e^{2|x|}+1)); overflow of exp -> inf -> result +-1. Safe for all x.
    float ax = fabsf(x);
    float e  = __expf(2.0f * ax);
    float r  = 1.0f - 2.0f / (e + 1.0f);
    return copysignf(r, x);
}

__global__ void __launch_bounds__(NTHR)
rnn_kernel(const float* __restrict__ inputs, const int* __restrict__ y,
           const int* __restrict__ order,  const float* __restrict__ U,
           const float* __restrict__ W,    const float* __restrict__ bias,
           const float* __restrict__ lin_w, const float* __restrict__ lin_b,
           float* __restrict__ hbuf,        // [2][BATCH][HID] double buffer
           unsigned int* __restrict__ cnt,  // [NGRP*CNT_STRIDE] barrier counters (zeroed)
           float* __restrict__ gloss, float* __restrict__ gcorr)
{
    extern __shared__ float smem[];
    float* Wl = smem;             // [HID][JS]   (k-major, 64 consecutive cols)
    float* hl = smem + HID*JS;    // [BPG][HID] h stage; reused as partial[8][8][64]

    const int tid = threadIdx.x;
    const int bid = blockIdx.x;
    const int m   = bid >> 5;     // member 0..7  (column slice)
    const int g   = bid & 31;     // group 0..31  (bid%8==g%8 -> members likely share an XCD)
    const int jbase = m * JS;
    const int grow  = g * BPG;    // first global batch row of this group

    // ---- one-time: load W[:, jbase:jbase+64] into LDS (coalesced float4) ----
    for (int idx = tid; idx < HID*(JS/4); idx += NTHR) {
        int row = idx >> 4;          // 16 quads per row
        int c4  = idx & 15;
        *(float4*)&Wl[row*JS + c4*4] = *(const float4*)&W[row*HID + jbase + c4*4];
    }

    // k-loop mapping: wave = 64-wide k range; lane -> (jq 0..15, ks 0..3)
    const int wv = tid >> 6;
    const int ln = tid & 63;
    const int jq = ln & 15;
    const int ks = ln >> 4;
    const int kbase = wv*64 + ks*16;

    // reduction/output mapping: wave = batch row, lane = column
    const int rb = tid >> 6;
    const int rj = tid & 63;
    const float Ureg = U[jbase + rj];
    const float Breg = bias[jbase + rj];
    const float* xrow = inputs + (size_t)(grow + rb) * TSTEPS;

    __syncthreads();   // W ready

    unsigned int target = 0;
    for (int t = 0; t < TSTEPS; ++t) {
        const int pix = order[t];
        const float xv = xrow[pix];      // issued early, used after k-loop
        float sum;
        if (t == 0) {
            sum = 0.0f;                  // h0 = 0
        } else {
            const int rbuf = (t + 1) & 1;    // buffer written at step t-1
            // stage group's h[8][512] into LDS (16 KB, coalesced)
            const float4* src = (const float4*)(hbuf + (size_t)rbuf*BATCH*HID + (size_t)grow*HID);
            float4* dst = (float4*)hl;
            dst[tid]        = src[tid];
            dst[tid + NTHR] = src[tid + NTHR];
            __syncthreads();

            float acc[BPG][4];
            #pragma unroll
            for (int b = 0; b < BPG; ++b) { acc[b][0]=0.f; acc[b][1]=0.f; acc[b][2]=0.f; acc[b][3]=0.f; }

            #pragma unroll
            for (int kk = 0; kk < 16; kk += 4) {
                const int k0 = kbase + kk;
                float4 w0 = *(float4*)&Wl[(k0+0)*JS + jq*4];
                float4 w1 = *(float4*)&Wl[(k0+1)*JS + jq*4];
                float4 w2 = *(float4*)&Wl[(k0+2)*JS + jq*4];
                float4 w3 = *(float4*)&Wl[(k0+3)*JS + jq*4];
                #pragma unroll
                for (int b = 0; b < BPG; ++b) {
                    float4 hv = *(float4*)&hl[b*HID + k0];
                    acc[b][0] = fmaf(hv.w,w3.x, fmaf(hv.z,w2.x, fmaf(hv.y,w1.x, fmaf(hv.x,w0.x, acc[b][0]))));
                    acc[b][1] = fmaf(hv.w,w3.y, fmaf(hv.z,w2.y, fmaf(hv.y,w1.y, fmaf(hv.x,w0.y, acc[b][1]))));
                    acc[b][2] = fmaf(hv.w,w3.z, fmaf(hv.z,w2.z, fmaf(hv.y,w1.z, fmaf(hv.x,w0.z, acc[b][2]))));
                    acc[b][3] = fmaf(hv.w,w3.w, fmaf(hv.z,w2.w, fmaf(hv.y,w1.w, fmaf(hv.x,w0.w, acc[b][3]))));
                }
            }
            __syncthreads();   // everyone done reading hl

            // reduce over ks (lanes ^16, ^32 hold the other k-subranges)
            #pragma unroll
            for (int b = 0; b < BPG; ++b) {
                #pragma unroll
                for (int jj = 0; jj < 4; ++jj) {
                    float v = acc[b][jj];
                    v += __shfl_xor(v, 16, 64);
                    v += __shfl_xor(v, 32, 64);
                    acc[b][jj] = v;
                }
            }
            if (ks == 0) {     // partial[wv][b][j]
                #pragma unroll
                for (int b = 0; b < BPG; ++b)
                    *(float4*)&hl[wv*512 + b*64 + jq*4] =
                        make_float4(acc[b][0], acc[b][1], acc[b][2], acc[b][3]);
            }
            __syncthreads();

            sum = 0.0f;
            #pragma unroll
            for (int w = 0; w < 8; ++w) sum += hl[w*512 + rb*64 + rj];
        }

        const float pre  = fmaf(xv, Ureg, sum + Breg);
        const float hval = fast_tanh(pre);
        const int wbuf = t & 1;
        hbuf[(size_t)wbuf*BATCH*HID + (size_t)(grow + rb)*HID + jbase + rj] = hval;

        __syncthreads();       // all global h writes issued (vmcnt drained at barrier)
        target += MEMB;
        if (tid == 0) {
            __builtin_amdgcn_fence(__ATOMIC_RELEASE, "agent");   // push h to coherent point
            __hip_atomic_fetch_add(&cnt[g*CNT_STRIDE], 1u, __ATOMIC_RELAXED, __HIP_MEMORY_SCOPE_AGENT);
            while (__hip_atomic_load(&cnt[g*CNT_STRIDE], __ATOMIC_RELAXED, __HIP_MEMORY_SCOPE_AGENT) < target) { }
            __builtin_amdgcn_fence(__ATOMIC_ACQUIRE, "agent");   // invalidate stale cached h
        }
        __syncthreads();
    }

    // ---- tail: member 0 of each group computes logits / loss / correct ----
    if (m == 0) {
        const int fbuf = (TSTEPS - 1) & 1;
        const float4* src = (const float4*)(hbuf + (size_t)fbuf*BATCH*HID + (size_t)grow*HID);
        float4* dst = (float4*)hl;
        dst[tid]        = src[tid];
        dst[tid + NTHR] = src[tid + NTHR];
        __syncthreads();

        __shared__ float lg[BPG][NCLS];
        __shared__ float sl[BPG], sc[BPG];
        if (tid < BPG*NCLS) {
            int b = tid / NCLS, c = tid - b*NCLS;
            float s = lin_b[c];
            for (int k = 0; k < HID; ++k)
                s = fmaf(hl[b*HID + k], lin_w[k*NCLS + c], s);
            lg[b][c] = s;
        }
        __syncthreads();
        if (tid < BPG) {
            int b = tid;
            float mx = lg[b][0]; int bi = 0;
            #pragma unroll
            for (int c = 1; c < NCLS; ++c) if (lg[b][c] > mx) { mx = lg[b][c]; bi = c; }
            float se = 0.f;
            #pragma unroll
            for (int c = 0; c < NCLS; ++c) se += __expf(lg[b][c] - mx);
            float lse = mx + __logf(se);
            int yy = y[grow + b];
            sl[b] = lse - lg[b][yy];              // -log p(y)
            sc[b] = (bi == yy) ? 1.0f : 0.0f;
        }
        __syncthreads();
        if (tid == 0) {
            float L = 0.f, C = 0.f;
            for (int b = 0; b < BPG; ++b) { L += sl[b]; C += sc[b]; }
            gloss[g] = L; gcorr[g] = C;
        }
    }
}

__global__ void init_kernel(unsigned int* cnt, float* gloss, float* gcorr) {
    int i = threadIdx.x;
    if (i < NGRP*CNT_STRIDE) cnt[i] = 0u;     // barrier counters MUST start at 0
    if (i < NGRP) { gloss[i] = 0.f; gcorr[i] = 0.f; }
}

__global__ void final_kernel(const float* gloss, const float* gcorr, float* out) {
    float L = 0.f, C = 0.f;
    for (int g = 0; g < NGRP; ++g) { L += gloss[g]; C += gcorr[g]; }
    out[0] = L / (float)BATCH;   // loss = mean(lse - logit_y)
    out[1] = C;                  // correct count
}

extern "C" void kernel_launch(void* const* d_in, const int* in_sizes, int n_in,
                              void* d_out, int out_size, void* d_ws, size_t ws_size,
                              hipStream_t stream)
{
    (void)in_sizes; (void)n_in; (void)out_size; (void)ws_size;
    const float* inputs = (const float*)d_in[0];
    const int*   y      = (const int*)  d_in[1];
    const int*   order  = (const int*)  d_in[2];
    const float* U      = (const float*)d_in[3];
    const float* W      = (const float*)d_in[4];
    const float* bias   = (const float*)d_in[5];
    const float* lin_w  = (const float*)d_in[6];
    const float* lin_b  = (const float*)d_in[7];
    float* out = (float*)d_out;

    char* ws = (char*)d_ws;
    float*        hbuf  = (float*)ws;                                   // 2*256*512*4 = 1 MB
    unsigned int* cnt   = (unsigned int*)(ws + 2*BATCH*HID*4);          // 4 KB padded counters
    float*        gloss = (float*)(ws + 2*BATCH*HID*4 + NGRP*CNT_STRIDE*4);
    float*        gcorr = gloss + NGRP;

    const int smem_bytes = SMEM_FLOATS * 4;   // 147456 B dynamic LDS (needs opt-in >64KB)
    (void)hipFuncSetAttribute((const void*)rnn_kernel,
                              hipFuncAttributeMaxDynamicSharedMemorySize, smem_bytes);

    init_kernel<<<1, 1024, 0, stream>>>(cnt, gloss, gcorr);
    rnn_kernel<<<NBLK, NTHR, smem_bytes, stream>>>(inputs, y, order, U, W, bias,
                                                   lin_w, lin_b, hbuf, cnt, gloss, gcorr);
    final_kernel<<<1, 1, 0, stream>>>(gloss, gcorr, out);
}

// Round 5
// 3364.486 us; speedup vs baseline: 1.8975x; 1.8975x over previous
//
#include <hip/hip_runtime.h>
#include <math.h>

// Problem constants (B=256, T=784, H=512, C=10)
#define TSTEPS 784
#define BATCH  256
#define HID    512
#define NCLS   10

// Decomposition: 32 groups x 8 member-blocks. Each member owns a 64-column
// slice of W held ENTIRELY IN REGISTERS (16 float4 per thread); each group
// owns 8 batch rows. Per step each block computes h_new[8 x 64cols]; groups
// exchange h via a double-buffered global buffer accessed ONLY with relaxed
// agent-scope atomics (bypass incoherent caches -> coherent point, no
// buffer_wbl2/buffer_inv fences), plus an 8-party atomic-counter barrier.
#define NBLK   256
#define NGRP   32
#define MEMB   8
#define BPG    8     // batch rows per group
#define JS     64    // output columns per block
#define NTHR   512
#define CNT_STRIDE 32        // pad barrier counters to 128 B

// 96 KB dynamic LDS: logical use is only 16 KB (h stage / partials), the rest
// guarantees 1 block/CU (2x96 > 160 KB) so no CU hosts two barrier-coupled blocks.
#define SMEM_BYTES (96*1024)

__device__ __forceinline__ float fast_tanh(float x) {
    // tanh(x) = sign(x) * (1 - 2/(e^{2|x|}+1)); exp overflow -> inf -> +-1. Safe.
    float ax = fabsf(x);
    float e  = __expf(2.0f * ax);
    float r  = 1.0f - 2.0f / (e + 1.0f);
    return copysignf(r, x);
}

__device__ __forceinline__ float coh_load(const float* p) {
    return __hip_atomic_load(p, __ATOMIC_RELAXED, __HIP_MEMORY_SCOPE_AGENT);
}
__device__ __forceinline__ void coh_store(float* p, float v) {
    __hip_atomic_store(p, v, __ATOMIC_RELAXED, __HIP_MEMORY_SCOPE_AGENT);
}

__global__ void __launch_bounds__(NTHR)
rnn_kernel(const float* __restrict__ inputs, const int* __restrict__ y,
           const int* __restrict__ order,  const float* __restrict__ U,
           const float* __restrict__ W,    const float* __restrict__ bias,
           const float* __restrict__ lin_w, const float* __restrict__ lin_b,
           float* __restrict__ hbuf,        // [2][BATCH][HID] double buffer (coherent access only)
           unsigned int* __restrict__ cnt,  // [NGRP*CNT_STRIDE] barrier counters (zeroed)
           float* __restrict__ gloss, float* __restrict__ gcorr)
{
    extern __shared__ float hl[];   // [BPG][HID] h stage; reused as partial[8][8][64]

    const int tid = threadIdx.x;
    const int bid = blockIdx.x;
    const int m   = bid >> 5;     // member 0..7  (column slice)
    const int g   = bid & 31;     // group 0..31  (members share bid%8 -> same XCD)
    const int jbase = m * JS;
    const int grow  = g * BPG;    // first global batch row of this group

    // k-loop mapping: wave = 64-wide k range; lane -> (jq 0..15, ks 0..3)
    const int wv = tid >> 6;
    const int ln = tid & 63;
    const int jq = ln & 15;
    const int ks = ln >> 4;
    const int kbase = wv*64 + ks*16;

    // ---- one-time: this thread's W tile (16 k-rows x 4 cols) into registers ----
    float4 wreg[16];
    #pragma unroll
    for (int r = 0; r < 16; ++r)
        wreg[r] = *(const float4*)&W[(size_t)(kbase + r)*HID + jbase + jq*4];

    // reduction/output mapping: wave = batch row, lane = column
    const int rb = tid >> 6;
    const int rj = tid & 63;
    const float Ureg = U[jbase + rj];
    const float Breg = bias[jbase + rj];
    const float* xrow = inputs + (size_t)(grow + rb) * TSTEPS;
    float* hout = hbuf + (size_t)(grow + rb)*HID + jbase + rj;   // + wbuf*BATCH*HID

    unsigned int target = 0;
    for (int t = 0; t < TSTEPS; ++t) {
        const int pix = order[t];
        const float xv = xrow[pix];      // issued early, used after k-loop
        float sum;
        if (t == 0) {
            sum = 0.0f;                  // h0 = 0
        } else {
            const int rbuf = (t + 1) & 1;    // buffer written at step t-1
            // stage group's h[8][512] into LDS via coherent loads (coalesced)
            const float* src = hbuf + (size_t)rbuf*BATCH*HID + (size_t)grow*HID;
            float stg[8];
            #pragma unroll
            for (int q = 0; q < 8; ++q) stg[q] = coh_load(src + tid + q*NTHR);
            #pragma unroll
            for (int q = 0; q < 8; ++q) hl[tid + q*NTHR] = stg[q];
            __syncthreads();

            float acc[BPG][4];
            #pragma unroll
            for (int b = 0; b < BPG; ++b) { acc[b][0]=0.f; acc[b][1]=0.f; acc[b][2]=0.f; acc[b][3]=0.f; }

            #pragma unroll
            for (int kk = 0; kk < 16; kk += 4) {
                const int k0 = kbase + kk;
                const float4 w0 = wreg[kk+0];
                const float4 w1 = wreg[kk+1];
                const float4 w2 = wreg[kk+2];
                const float4 w3 = wreg[kk+3];
                #pragma unroll
                for (int b = 0; b < BPG; ++b) {
                    float4 hv = *(float4*)&hl[b*HID + k0];   // 16-lane broadcast, 2-way max
                    acc[b][0] = fmaf(hv.w,w3.x, fmaf(hv.z,w2.x, fmaf(hv.y,w1.x, fmaf(hv.x,w0.x, acc[b][0]))));
                    acc[b][1] = fmaf(hv.w,w3.y, fmaf(hv.z,w2.y, fmaf(hv.y,w1.y, fmaf(hv.x,w0.y, acc[b][1]))));
                    acc[b][2] = fmaf(hv.w,w3.z, fmaf(hv.z,w2.z, fmaf(hv.y,w1.z, fmaf(hv.x,w0.z, acc[b][2]))));
                    acc[b][3] = fmaf(hv.w,w3.w, fmaf(hv.z,w2.w, fmaf(hv.y,w1.w, fmaf(hv.x,w0.w, acc[b][3]))));
                }
            }
            __syncthreads();   // everyone done reading hl

            // reduce over ks (lanes ^16, ^32 hold the other k-subranges)
            #pragma unroll
            for (int b = 0; b < BPG; ++b) {
                #pragma unroll
                for (int jj = 0; jj < 4; ++jj) {
                    float v = acc[b][jj];
                    v += __shfl_xor(v, 16, 64);
                    v += __shfl_xor(v, 32, 64);
                    acc[b][jj] = v;
                }
            }
            if (ks == 0) {     // partial[wv][b][j]
                #pragma unroll
                for (int b = 0; b < BPG; ++b)
                    *(float4*)&hl[wv*512 + b*64 + jq*4] =
                        make_float4(acc[b][0], acc[b][1], acc[b][2], acc[b][3]);
            }
            __syncthreads();

            sum = 0.0f;
            #pragma unroll
            for (int w = 0; w < 8; ++w) sum += hl[w*512 + rb*64 + rj];
        }

        const float pre  = fmaf(xv, Ureg, sum + Breg);
        const float hval = fast_tanh(pre);
        const int wbuf = t & 1;
        coh_store(hout + (size_t)wbuf*BATCH*HID, hval);   // straight to coherent point

        __syncthreads();       // every thread drained its own vmcnt -> all h stores committed
        target += MEMB;
        if (tid == 0) {
            __hip_atomic_fetch_add(&cnt[g*CNT_STRIDE], 1u, __ATOMIC_RELAXED, __HIP_MEMORY_SCOPE_AGENT);
            while (__hip_atomic_load(&cnt[g*CNT_STRIDE], __ATOMIC_RELAXED, __HIP_MEMORY_SCOPE_AGENT) < target) { }
        }
        __syncthreads();
    }

    // ---- tail: member 0 of each group computes logits / loss / correct ----
    if (m == 0) {
        const int fbuf = (TSTEPS - 1) & 1;
        const float* src = hbuf + (size_t)fbuf*BATCH*HID + (size_t)grow*HID;
        float stg[8];
        #pragma unroll
        for (int q = 0; q < 8; ++q) stg[q] = coh_load(src + tid + q*NTHR);
        #pragma unroll
        for (int q = 0; q < 8; ++q) hl[tid + q*NTHR] = stg[q];
        __syncthreads();

        __shared__ float lg[BPG][NCLS];
        __shared__ float sl[BPG], sc[BPG];
        if (tid < BPG*NCLS) {
            int b = tid / NCLS, c = tid - b*NCLS;
            float s = lin_b[c];
            for (int k = 0; k < HID; ++k)
                s = fmaf(hl[b*HID + k], lin_w[k*NCLS + c], s);
            lg[b][c] = s;
        }
        __syncthreads();
        if (tid < BPG) {
            int b = tid;
            float mx = lg[b][0]; int bi = 0;
            #pragma unroll
            for (int c = 1; c < NCLS; ++c) if (lg[b][c] > mx) { mx = lg[b][c]; bi = c; }
            float se = 0.f;
            #pragma unroll
            for (int c = 0; c < NCLS; ++c) se += __expf(lg[b][c] - mx);
            float lse = mx + __logf(se);
            int yy = y[grow + b];
            sl[b] = lse - lg[b][yy];              // -log p(y)
            sc[b] = (bi == yy) ? 1.0f : 0.0f;
        }
        __syncthreads();
        if (tid == 0) {
            float L = 0.f, C = 0.f;
            for (int b = 0; b < BPG; ++b) { L += sl[b]; C += sc[b]; }
            gloss[g] = L; gcorr[g] = C;
        }
    }
}

__global__ void init_kernel(unsigned int* cnt, float* gloss, float* gcorr) {
    int i = threadIdx.x;
    if (i < NGRP*CNT_STRIDE) cnt[i] = 0u;     // barrier counters MUST start at 0
    if (i < NGRP) { gloss[i] = 0.f; gcorr[i] = 0.f; }
}

__global__ void final_kernel(const float* gloss, const float* gcorr, float* out) {
    float L = 0.f, C = 0.f;
    for (int g = 0; g < NGRP; ++g) { L += gloss[g]; C += gcorr[g]; }
    out[0] = L / (float)BATCH;   // loss = mean(lse - logit_y)
    out[1] = C;                  // correct count
}

extern "C" void kernel_launch(void* const* d_in, const int* in_sizes, int n_in,
                              void* d_out, int out_size, void* d_ws, size_t ws_size,
                              hipStream_t stream)
{
    (void)in_sizes; (void)n_in; (void)out_size; (void)ws_size;
    const float* inputs = (const float*)d_in[0];
    const int*   y      = (const int*)  d_in[1];
    const int*   order  = (const int*)  d_in[2];
    const float* U      = (const float*)d_in[3];
    const float* W      = (const float*)d_in[4];
    const float* bias   = (const float*)d_in[5];
    const float* lin_w  = (const float*)d_in[6];
    const float* lin_b  = (const float*)d_in[7];
    float* out = (float*)d_out;

    char* ws = (char*)d_ws;
    float*        hbuf  = (float*)ws;                                   // 2*256*512*4 = 1 MB
    unsigned int* cnt   = (unsigned int*)(ws + 2*BATCH*HID*4);          // 4 KB padded counters
    float*        gloss = (float*)(ws + 2*BATCH*HID*4 + NGRP*CNT_STRIDE*4);
    float*        gcorr = gloss + NGRP;

    (void)hipFuncSetAttribute((const void*)rnn_kernel,
                              hipFuncAttributeMaxDynamicSharedMemorySize, SMEM_BYTES);

    init_kernel<<<1, 1024, 0, stream>>>(cnt, gloss, gcorr);
    rnn_kernel<<<NBLK, NTHR, SMEM_BYTES, stream>>>(inputs, y, order, U, W, bias,
                                                   lin_w, lin_b, hbuf, cnt, gloss, gcorr);
    final_kernel<<<1, 1, 0, stream>>>(gloss, gcorr, out);
}

// Round 7
// 3311.812 us; speedup vs baseline: 1.9277x; 1.0159x over previous
//
#include <hip/hip_runtime.h>
#include <math.h>

// Problem constants (B=256, T=784, H=512, C=10)
#define TSTEPS 784
#define BATCH  256
#define HID    512
#define NCLS   10

// Decomposition: 32 groups x 8 member-blocks. Each member owns a 64-column
// slice of W in REGISTERS (16 float4/thread); each group owns 8 batch rows.
// h exchange: TAGGED PAIRS — each h element stored as 8B (tag=step, value)
// with one relaxed agent-scope 64-bit store (fire-and-forget). Consumers
// load pairs and retry until tag == t-1. No fences, no atomics RMW, no
// counter barrier: validity travels with the data (1 MALL RTT per step).
// Double-buffer safety comes from dataflow: a member reaches step t+2's
// writes only after validating ALL of h_{t+1}, which implies every member
// finished reading h_t.
#define NBLK   256
#define NGRP   32
#define MEMB   8
#define BPG    8     // batch rows per group
#define JS     64    // output columns per block
#define NTHR   512
#define GH     (BPG*HID)   // pairs per group per buffer = 4096

// 96 KB dynamic LDS: logical use is 32 KB (h stage + partials); the rest
// guarantees 1 block/CU so no CU hosts two dataflow-coupled blocks.
#define SMEM_BYTES (96*1024)

__device__ __forceinline__ float fast_tanh(float x) {
    // tanh(x) = sign(x)*(1 - 2/(e^{2|x|}+1)); exp overflow -> inf -> +-1. Safe.
    float ax = fabsf(x);
    float e  = __expf(2.0f * ax);
    float r  = 1.0f - 2.0f / (e + 1.0f);
    return copysignf(r, x);
}

__device__ __forceinline__ unsigned long long coh_load64(const unsigned long long* p) {
    return __hip_atomic_load(p, __ATOMIC_RELAXED, __HIP_MEMORY_SCOPE_AGENT);
}
__device__ __forceinline__ void coh_store64(unsigned long long* p, unsigned long long v) {
    __hip_atomic_store(p, v, __ATOMIC_RELAXED, __HIP_MEMORY_SCOPE_AGENT);
}

// Validated group-h stage: load 8 pairs/thread (strided, coalesced), retry
// stale tags, write values to hl[tid + q*NTHR]. hl layout = [b][k] (b*512+k).
__device__ __forceinline__ void stage_group_h(const unsigned long long* src,
                                              unsigned int exp_tag, float* hl,
                                              int tid)
{
    unsigned long long v[8];
    unsigned int ok = 0;
    while (ok != 0xFFu) {
        #pragma unroll
        for (int q = 0; q < 8; ++q)
            if (!(ok & (1u << q))) v[q] = coh_load64(src + tid + q*NTHR);
        #pragma unroll
        for (int q = 0; q < 8; ++q)
            if (!(ok & (1u << q)) && (unsigned int)(v[q] >> 32) == exp_tag)
                ok |= 1u << q;
    }
    #pragma unroll
    for (int q = 0; q < 8; ++q)
        hl[tid + q*NTHR] = __uint_as_float((unsigned int)v[q]);
}

__global__ void __launch_bounds__(NTHR)
rnn_kernel(const float* __restrict__ inputs, const int* __restrict__ y,
           const int* __restrict__ order,  const float* __restrict__ U,
           const float* __restrict__ W,    const float* __restrict__ bias,
           const float* __restrict__ lin_w, const float* __restrict__ lin_b,
           unsigned long long* __restrict__ pairs, // [2][BATCH][HID] (tag,val) pairs
           float* __restrict__ gloss, float* __restrict__ gcorr)
{
    extern __shared__ float smem[];
    float* hl   = smem;          // [BPG][HID] staged h values (16 KB)
    float* part = smem + GH;     // partial[8 waves][BPG][JS]   (16 KB)

    const int tid = threadIdx.x;
    const int bid = blockIdx.x;
    const int m   = bid >> 5;     // member 0..7  (column slice)
    const int g   = bid & 31;     // group 0..31  (members share bid%8 -> same XCD)
    const int jbase = m * JS;
    const int grow  = g * BPG;    // first global batch row of this group

    // k-loop mapping: wave = 64-wide k chunk; lane -> (jq 0..15, ks 0..3)
    const int wv = tid >> 6;
    const int ln = tid & 63;
    const int jq = ln & 15;
    const int ks = ln >> 4;
    const int kbase = wv*64 + ks*16;

    // ---- one-time: this thread's W tile (16 k-rows x 4 cols) into registers ----
    float4 wreg[16];
    #pragma unroll
    for (int r = 0; r < 16; ++r)
        wreg[r] = *(const float4*)&W[(size_t)(kbase + r)*HID + jbase + jq*4];

    // reduction/output mapping: wave = batch row, lane = column
    const int rb = tid >> 6;
    const int rj = tid & 63;
    const float Ureg = U[jbase + rj];
    const float Breg = bias[jbase + rj];
    const float* xrow = inputs + (size_t)(grow + rb) * TSTEPS;
    unsigned long long* pout = pairs + (size_t)(grow + rb)*HID + jbase + rj; // + buf*BATCH*HID
    const unsigned long long* gsrc = pairs + (size_t)grow*HID;               // + buf*BATCH*HID

    for (int t = 0; t < TSTEPS; ++t) {
        const int pix = order[t];
        const float xv = xrow[pix];      // issued early, used after k-loop
        float sum;
        if (t == 0) {
            sum = 0.0f;                  // h0 = 0
        } else {
            // ---- validated stage of h_{t-1} (replaces barrier + fence chain) ----
            const int rbuf = (t - 1) & 1;
            stage_group_h(gsrc + (size_t)rbuf*BATCH*HID, (unsigned int)(t - 1), hl, tid);
            __syncthreads();   // (1) hl ready; also separates prev sum-reads from part-writes

            float acc[BPG][4];
            #pragma unroll
            for (int b = 0; b < BPG; ++b) { acc[b][0]=0.f; acc[b][1]=0.f; acc[b][2]=0.f; acc[b][3]=0.f; }

            #pragma unroll
            for (int kk = 0; kk < 16; kk += 4) {
                const int k0 = kbase + kk;
                const float4 w0 = wreg[kk+0];
                const float4 w1 = wreg[kk+1];
                const float4 w2 = wreg[kk+2];
                const float4 w3 = wreg[kk+3];
                #pragma unroll
                for (int b = 0; b < BPG; ++b) {
                    float4 hv = *(float4*)&hl[b*HID + k0];   // 16-lane broadcast
                    acc[b][0] = fmaf(hv.w,w3.x, fmaf(hv.z,w2.x, fmaf(hv.y,w1.x, fmaf(hv.x,w0.x, acc[b][0]))));
                    acc[b][1] = fmaf(hv.w,w3.y, fmaf(hv.z,w2.y, fmaf(hv.y,w1.y, fmaf(hv.x,w0.y, acc[b][1]))));
                    acc[b][2] = fmaf(hv.w,w3.z, fmaf(hv.z,w2.z, fmaf(hv.y,w1.z, fmaf(hv.x,w0.z, acc[b][2]))));
                    acc[b][3] = fmaf(hv.w,w3.w, fmaf(hv.z,w2.w, fmaf(hv.y,w1.w, fmaf(hv.x,w0.w, acc[b][3]))));
                }
            }

            // reduce over ks (lanes ^16, ^32 hold the other k-subranges)
            #pragma unroll
            for (int b = 0; b < BPG; ++b) {
                #pragma unroll
                for (int jj = 0; jj < 4; ++jj) {
                    float v = acc[b][jj];
                    v += __shfl_xor(v, 16, 64);
                    v += __shfl_xor(v, 32, 64);
                    acc[b][jj] = v;
                }
            }
            if (ks == 0) {     // part[wv][b][j]
                #pragma unroll
                for (int b = 0; b < BPG; ++b)
                    *(float4*)&part[wv*512 + b*64 + jq*4] =
                        make_float4(acc[b][0], acc[b][1], acc[b][2], acc[b][3]);
            }
            __syncthreads();   // (2) partials ready

            sum = 0.0f;
            #pragma unroll
            for (int w = 0; w < 8; ++w) sum += part[w*512 + rb*64 + rj];
        }

        const float pre  = fmaf(xv, Ureg, sum + Breg);
        const float hval = fast_tanh(pre);
        const unsigned long long pv =
            ((unsigned long long)(unsigned int)t << 32) | __float_as_uint(hval);
        coh_store64(pout + (size_t)(t & 1)*BATCH*HID, pv);   // fire-and-forget
    }

    // ---- tail: member 0 of each group computes logits / loss / correct ----
    if (m == 0) {
        const int fbuf = (TSTEPS - 1) & 1;
        __syncthreads();   // all waves past last part-read before reusing hl
        stage_group_h(gsrc + (size_t)fbuf*BATCH*HID, (unsigned int)(TSTEPS - 1), hl, tid);
        __syncthreads();

        __shared__ float lg[BPG][NCLS];
        __shared__ float sl[BPG], sc[BPG];
        if (tid < BPG*NCLS) {
            int b = tid / NCLS, c = tid - b*NCLS;
            float s = lin_b[c];
            for (int k = 0; k < HID; ++k)
                s = fmaf(hl[b*HID + k], lin_w[k*NCLS + c], s);
            lg[b][c] = s;
        }
        __syncthreads();
        if (tid < BPG) {
            int b = tid;
            float mx = lg[b][0]; int bi = 0;
            #pragma unroll
            for (int c = 1; c < NCLS; ++c) if (lg[b][c] > mx) { mx = lg[b][c]; bi = c; }
            float se = 0.f;
            #pragma unroll
            for (int c = 0; c < NCLS; ++c) se += __expf(lg[b][c] - mx);
            float lse = mx + __logf(se);
            int yy = y[grow + b];
            sl[b] = lse - lg[b][yy];              // -log p(y)
            sc[b] = (bi == yy) ? 1.0f : 0.0f;
        }
        __syncthreads();
        if (tid == 0) {
            float L = 0.f, C = 0.f;
            for (int b = 0; b < BPG; ++b) { L += sl[b]; C += sc[b]; }
            gloss[g] = L; gcorr[g] = C;
        }
    }
}

__global__ void final_kernel(const float* gloss, const float* gcorr, float* out) {
    float L = 0.f, C = 0.f;
    for (int g = 0; g < NGRP; ++g) { L += gloss[g]; C += gcorr[g]; }
    out[0] = L / (float)BATCH;   // loss = mean(lse - logit_y)
    out[1] = C;                  // correct count
}

extern "C" void kernel_launch(void* const* d_in, const int* in_sizes, int n_in,
                              void* d_out, int out_size, void* d_ws, size_t ws_size,
                              hipStream_t stream)
{
    (void)in_sizes; (void)n_in; (void)out_size; (void)ws_size;
    const float* inputs = (const float*)d_in[0];
    const int*   y      = (const int*)  d_in[1];
    const int*   order  = (const int*)  d_in[2];
    const float* U      = (const float*)d_in[3];
    const float* W      = (const float*)d_in[4];
    const float* bias   = (const float*)d_in[5];
    const float* lin_w  = (const float*)d_in[6];
    const float* lin_b  = (const float*)d_in[7];
    float* out = (float*)d_out;

    char* ws = (char*)d_ws;
    unsigned long long* pairs = (unsigned long long*)ws;        // 2*256*512*8 = 2 MB
    float* gloss = (float*)(ws + 2*(size_t)BATCH*HID*8);
    float* gcorr = gloss + NGRP;
    // NOTE: ws is re-poisoned to 0xAA before every launch -> pair tags start
    // at 0xAAAAAAAA which never equals a step tag (0..783). No init needed.

    (void)hipFuncSetAttribute((const void*)rnn_kernel,
                              hipFuncAttributeMaxDynamicSharedMemorySize, SMEM_BYTES);

    rnn_kernel<<<NBLK, NTHR, SMEM_BYTES, stream>>>(inputs, y, order, U, W, bias,
                                                   lin_w, lin_b, pairs, gloss, gcorr);
    final_kernel<<<1, 1, 0, stream>>>(gloss, gcorr, out);
}

// Round 10
// 2939.774 us; speedup vs baseline: 2.1717x; 1.1266x over previous
//
#include <hip/hip_runtime.h>
#include <math.h>

// Problem constants (B=256, T=784, H=512, C=10)
#define TSTEPS 784
#define BATCH  256
#define HID    512
#define NCLS   10

// 32 groups x 8 member-blocks. Member m holds W[:, m*64..m*64+64) in
// REGISTERS; each group owns 8 batch rows. h exchange: tagged 8B pairs
// (tag=step | f32 value) via relaxed agent-scope atomics.
//
// KEY STRUCTURE (this round): wave wv consumes exactly k-chunk wv = the
// slice produced by member wv. So each wave polls ONLY slice wv (per-wave
// independent, overlaps with the co-resident wave's compute on the SIMD),
// and member m's own slice is passed through LDS (wave m never polls MALL).
//
// Overwrite safety (no barrier across members): member M stores slice@t+2
// over slice@t only after M's B1 at t+2, which requires all M's waves
// validated h_{t+1} of ALL members S; S stored h_{t+1} only after S's B1
// at t+1, which required S's wave-M validating slice M@t. So every
// consumer finished reading slice@t before it is overwritten.
#define NBLK   256
#define NGRP   32
#define MEMB   8
#define BPG    8     // batch rows per group
#define JS     64    // output columns per block
#define NTHR   512

// 96 KB dynamic LDS: logical use is 32 KB (hl + part); the rest guarantees
// 1 block/CU so no CU hosts two dataflow-coupled blocks.
#define SMEM_BYTES (96*1024)

__device__ __forceinline__ float fast_tanh(float x) {
    // tanh(x) = sign(x)*(1 - 2/(e^{2|x|}+1)); exp overflow -> inf -> +-1. Safe.
    float ax = fabsf(x);
    float e  = __expf(2.0f * ax);
    float r  = 1.0f - 2.0f / (e + 1.0f);
    return copysignf(r, x);
}

__device__ __forceinline__ unsigned long long coh_load64(const unsigned long long* p) {
    return __hip_atomic_load(p, __ATOMIC_RELAXED, __HIP_MEMORY_SCOPE_AGENT);
}
__device__ __forceinline__ void coh_store64(unsigned long long* p, unsigned long long v) {
    __hip_atomic_store(p, v, __ATOMIC_RELAXED, __HIP_MEMORY_SCOPE_AGENT);
}

// Tail-only: stage full group h [8][512] (all slices) into dst[b*HID+k].
__device__ __forceinline__ void stage_group_h(const unsigned long long* src,
                                              unsigned int exp_tag, float* dst,
                                              int tid)
{
    unsigned long long v[8];
    unsigned int ok = 0;
    while (ok != 0xFFu) {
        #pragma unroll
        for (int q = 0; q < 8; ++q)
            if (!(ok & (1u << q))) v[q] = coh_load64(src + tid + q*NTHR);
        #pragma unroll
        for (int q = 0; q < 8; ++q)
            if (!(ok & (1u << q)) && (unsigned int)(v[q] >> 32) == exp_tag)
                ok |= 1u << q;
    }
    #pragma unroll
    for (int q = 0; q < 8; ++q)
        dst[tid + q*NTHR] = __uint_as_float((unsigned int)v[q]);
}

__global__ void __launch_bounds__(NTHR)
rnn_kernel(const float* __restrict__ inputs, const int* __restrict__ y,
           const int* __restrict__ order,  const float* __restrict__ U,
           const float* __restrict__ W,    const float* __restrict__ bias,
           const float* __restrict__ lin_w, const float* __restrict__ lin_b,
           unsigned long long* __restrict__ pairs, // [2][BATCH][HID] (tag,val)
           float* __restrict__ gloss, float* __restrict__ gcorr)
{
    extern __shared__ float smem[];
    float* hl   = smem;          // [wave][b][64]: staged h, region wv = slice wv (16 KB)
    float* part = smem + 4096;   // [wave][b][64] partials; tail reuses as [b][512] (16 KB)

    const int tid = threadIdx.x;
    const int bid = blockIdx.x;
    const int m   = bid >> 5;     // member 0..7  (column slice)
    const int g   = bid & 31;     // group 0..31
    const int jbase = m * JS;
    const int grow  = g * BPG;    // first global batch row of this group

    // k-loop mapping: wave wv covers k in [wv*64, wv*64+64); lane -> (jq, ks)
    const int wv = tid >> 6;
    const int ln = tid & 63;
    const int jq = ln & 15;
    const int ks = ln >> 4;
    const int kbase = wv*64 + ks*16;
    const int hbase = wv*512 + ks*16;     // LDS base of this thread's k-subrange

    // ---- one-time: this thread's W tile (16 k-rows x 4 cols) into registers ----
    float4 wreg[16];
    #pragma unroll
    for (int r = 0; r < 16; ++r)
        wreg[r] = *(const float4*)&W[(size_t)(kbase + r)*HID + jbase + jq*4];

    // output mapping: wave = batch row, lane = column
    const int rb = tid >> 6;
    const int rj = tid & 63;
    const float Ureg = U[jbase + rj];
    const float Breg = bias[jbase + rj];
    const float* xrow = inputs + (size_t)(grow + rb) * TSTEPS;
    unsigned long long* pout = pairs + (size_t)(grow + rb)*HID + jbase + rj; // + buf*BATCH*HID
    // poll source for wave wv: slice wv of the group's rows
    const unsigned long long* psrc = pairs + (size_t)grow*HID + wv*64 + ln;  // + buf*BATCH*HID + b*HID

    for (int t = 0; t < TSTEPS; ++t) {
        const int pix = order[t];
        const float xv = xrow[pix];      // issued early, used at the end
        float sum;
        if (t == 0) {
            sum = 0.0f;                  // h0 = 0
        } else {
            // ---- phase 1: per-wave poll of slice wv (skip own slice: in LDS) ----
            if (wv != m) {
                const unsigned long long* src = psrc + (size_t)((t-1) & 1)*BATCH*HID;
                const unsigned int etag = (unsigned int)(t - 1);
                unsigned long long v[8];
                unsigned int ok = 0;
                while (ok != 0xFFu) {
                    #pragma unroll
                    for (int b = 0; b < 8; ++b)
                        if (!(ok & (1u << b))) v[b] = coh_load64(src + (size_t)b*HID);
                    #pragma unroll
                    for (int b = 0; b < 8; ++b)
                        if (!(ok & (1u << b)) && (unsigned int)(v[b] >> 32) == etag)
                            ok |= 1u << b;
                }
                #pragma unroll
                for (int b = 0; b < 8; ++b)
                    hl[wv*512 + b*64 + ln] = __uint_as_float((unsigned int)v[b]);
            }
            // no barrier: each wave reads only its own hl region (wave m's was
            // written by all waves before last step's B2).

            // ---- phase 2: k-loop partials over this wave's k-chunk ----
            float acc[BPG][4];
            #pragma unroll
            for (int b = 0; b < BPG; ++b) { acc[b][0]=0.f; acc[b][1]=0.f; acc[b][2]=0.f; acc[b][3]=0.f; }

            #pragma unroll
            for (int kk = 0; kk < 16; kk += 4) {
                const float4 w0 = wreg[kk+0];
                const float4 w1 = wreg[kk+1];
                const float4 w2 = wreg[kk+2];
                const float4 w3 = wreg[kk+3];
                #pragma unroll
                for (int b = 0; b < BPG; ++b) {
                    float4 hv = *(float4*)&hl[hbase + b*64 + kk];   // 16-lane broadcast
                    acc[b][0] = fmaf(hv.w,w3.x, fmaf(hv.z,w2.x, fmaf(hv.y,w1.x, fmaf(hv.x,w0.x, acc[b][0]))));
                    acc[b][1] = fmaf(hv.w,w3.y, fmaf(hv.z,w2.y, fmaf(hv.y,w1.y, fmaf(hv.x,w0.y, acc[b][1]))));
                    acc[b][2] = fmaf(hv.w,w3.z, fmaf(hv.z,w2.z, fmaf(hv.y,w1.z, fmaf(hv.x,w0.z, acc[b][2]))));
                    acc[b][3] = fmaf(hv.w,w3.w, fmaf(hv.z,w2.w, fmaf(hv.y,w1.w, fmaf(hv.x,w0.w, acc[b][3]))));
                }
            }

            // ---- phase 3: reduce over ks within wave, write partials ----
            #pragma unroll
            for (int b = 0; b < BPG; ++b) {
                #pragma unroll
                for (int jj = 0; jj < 4; ++jj) {
                    float v = acc[b][jj];
                    v += __shfl_xor(v, 16, 64);
                    v += __shfl_xor(v, 32, 64);
                    acc[b][jj] = v;
                }
            }
            if (ks == 0) {
                #pragma unroll
                for (int b = 0; b < BPG; ++b)
                    *(float4*)&part[wv*512 + b*64 + jq*4] =
                        make_float4(acc[b][0], acc[b][1], acc[b][2], acc[b][3]);
            }
            __syncthreads();   // B1: partials ready

            // ---- phase 5: cross-wave sum ----
            sum = 0.0f;
            #pragma unroll
            for (int w = 0; w < 8; ++w) sum += part[w*512 + rb*64 + rj];
        }

        // ---- phase 6: activation, own-slice LDS pass, MALL store ----
        const float pre  = fmaf(xv, Ureg, sum + Breg);
        const float hval = fast_tanh(pre);
        hl[m*512 + rb*64 + rj] = hval;   // own slice -> wave m's region (next step)
        const unsigned long long pv =
            ((unsigned long long)(unsigned int)t << 32) | __float_as_uint(hval);
        coh_store64(pout + (size_t)(t & 1)*BATCH*HID, pv);   // fire-and-forget
        __syncthreads();   // B2: hl[m] complete before next step's reads; also
                           // separates part reads (phase 5) from next B1 writes
    }

    // ---- tail: member 0 of each group computes logits / loss / correct ----
    if (m == 0) {
        const int fbuf = (TSTEPS - 1) & 1;
        const unsigned long long* gsrc = pairs + (size_t)grow*HID;
        stage_group_h(gsrc + (size_t)fbuf*BATCH*HID, (unsigned int)(TSTEPS - 1), part, tid);
        __syncthreads();

        __shared__ float lg[BPG][NCLS];
        __shared__ float sl[BPG], sc[BPG];
        if (tid < BPG*NCLS) {
            int b = tid / NCLS, c = tid - b*NCLS;
            float s = lin_b[c];
            for (int k = 0; k < HID; ++k)
                s = fmaf(part[b*HID + k], lin_w[k*NCLS + c], s);
            lg[b][c] = s;
        }
        __syncthreads();
        if (tid < BPG) {
            int b = tid;
            float mx = lg[b][0]; int bi = 0;
            #pragma unroll
            for (int c = 1; c < NCLS; ++c) if (lg[b][c] > mx) { mx = lg[b][c]; bi = c; }
            float se = 0.f;
            #pragma unroll
            for (int c = 0; c < NCLS; ++c) se += __expf(lg[b][c] - mx);
            float lse = mx + __logf(se);
            int yy = y[grow + b];
            sl[b] = lse - lg[b][yy];              // -log p(y)
            sc[b] = (bi == yy) ? 1.0f : 0.0f;
        }
        __syncthreads();
        if (tid == 0) {
            float L = 0.f, C = 0.f;
            for (int b = 0; b < BPG; ++b) { L += sl[b]; C += sc[b]; }
            gloss[g] = L; gcorr[g] = C;
        }
    }
}

__global__ void final_kernel(const float* gloss, const float* gcorr, float* out) {
    float L = 0.f, C = 0.f;
    for (int g = 0; g < NGRP; ++g) { L += gloss[g]; C += gcorr[g]; }
    out[0] = L / (float)BATCH;   // loss = mean(lse - logit_y)
    out[1] = C;                  // correct count
}

extern "C" void kernel_launch(void* const* d_in, const int* in_sizes, int n_in,
                              void* d_out, int out_size, void* d_ws, size_t ws_size,
                              hipStream_t stream)
{
    (void)in_sizes; (void)n_in; (void)out_size; (void)ws_size;
    const float* inputs = (const float*)d_in[0];
    const int*   y      = (const int*)  d_in[1];
    const int*   order  = (const int*)  d_in[2];
    const float* U      = (const float*)d_in[3];
    const float* W      = (const float*)d_in[4];
    const float* bias   = (const float*)d_in[5];
    const float* lin_w  = (const float*)d_in[6];
    const float* lin_b  = (const float*)d_in[7];
    float* out = (float*)d_out;

    char* ws = (char*)d_ws;
    unsigned long long* pairs = (unsigned long long*)ws;        // 2*256*512*8 = 2 MB
    float* gloss = (float*)(ws + 2*(size_t)BATCH*HID*8);
    float* gcorr = gloss + NGRP;
    // ws re-poisoned to 0xAA before every launch -> pair tags start at
    // 0xAAAAAAAA, never equal to a step tag (0..783). No init needed.

    (void)hipFuncSetAttribute((const void*)rnn_kernel,
                              hipFuncAttributeMaxDynamicSharedMemorySize, SMEM_BYTES);

    rnn_kernel<<<NBLK, NTHR, SMEM_BYTES, stream>>>(inputs, y, order, U, W, bias,
                                                   lin_w, lin_b, pairs, gloss, gcorr);
    final_kernel<<<1, 1, 0, stream>>>(gloss, gcorr, out);
}